// Round 8
// baseline (229.132 us; speedup 1.0000x reference)
//
#include <hip/hip_runtime.h>
#include <hip/hip_bf16.h>

typedef unsigned short ushort_t;
typedef unsigned int uint32;
typedef __attribute__((ext_vector_type(8))) short short8;
typedef __attribute__((ext_vector_type(4))) float f32x4;

// Problem constants: B=2, S=2048, D=1024, H=16, DK=64
#define NB 2
#define NS 2048
#define ND 1024
#define NH 16

__device__ __forceinline__ float bf2f(ushort_t u) {
  return __uint_as_float(((uint32)u) << 16);
}
__device__ __forceinline__ ushort_t f2bf(float x) {
  uint32 u = __float_as_uint(x);
  uint32 r = u + 0x7FFFu + ((u >> 16) & 1u);  // RNE
  return (ushort_t)(r >> 16);
}

__device__ __forceinline__ void gload16(const void* g, void* l) {
  __builtin_amdgcn_global_load_lds(
      (const __attribute__((address_space(1))) void*)g,
      (__attribute__((address_space(3))) void*)l, 16, 0, 0);
}

// ---------------------------------------------------------------------------
// fp32 -> bf16 convert: q,k,v (2048 blocks each) + wk,wv,wo (512 each) = 7680.
// ---------------------------------------------------------------------------
__global__ __launch_bounds__(256) void convert_kernel(
    const float* q, const float* k, const float* v, const float* wk,
    const float* wv, const float* wo, ushort_t* Xq, ushort_t* Xk, ushort_t* Xv,
    ushort_t* Wk, ushort_t* Wv, ushort_t* Wo) {
  const int blk = blockIdx.x;
  const float* src;
  ushort_t* dst;
  int base;
  if (blk < 2048) { src = q; dst = Xq; base = blk; }
  else if (blk < 4096) { src = k; dst = Xk; base = blk - 2048; }
  else if (blk < 6144) { src = v; dst = Xv; base = blk - 4096; }
  else if (blk < 6656) { src = wk; dst = Wk; base = blk - 6144; }
  else if (blk < 7168) { src = wv; dst = Wv; base = blk - 6656; }
  else { src = wo; dst = Wo; base = blk - 7168; }
  const size_t off = (size_t)base * 2048 + (size_t)threadIdx.x * 8;
  const float4 v0 = *(const float4*)&src[off];
  const float4 v1 = *(const float4*)&src[off + 4];
  short8 o;
  o[0] = (short)f2bf(v0.x); o[1] = (short)f2bf(v0.y);
  o[2] = (short)f2bf(v0.z); o[3] = (short)f2bf(v0.w);
  o[4] = (short)f2bf(v1.x); o[5] = (short)f2bf(v1.y);
  o[6] = (short)f2bf(v1.z); o[7] = (short)f2bf(v1.w);
  *(short8*)&dst[off] = o;
}

// ---------------------------------------------------------------------------
// wq [1024k][1024d] fp32 -> WqT [1024d][1024k] bf16 via 64x64 LDS tiles.
// ---------------------------------------------------------------------------
__global__ __launch_bounds__(256) void transp_wq_kernel(const float* wq,
                                                        ushort_t* WqT) {
  const int tk = blockIdx.x >> 4, td = blockIdx.x & 15;
  __shared__ float sT[64][65];
  const int t = threadIdx.x;
  const int r = t >> 2;
  const int cbase = (t & 3) * 16;
  const float* src = wq + (size_t)(tk * 64 + r) * ND + td * 64 + cbase;
#pragma unroll
  for (int i = 0; i < 4; ++i) {
    const float4 v4 = *(const float4*)&src[i * 4];
    sT[cbase + i * 4 + 0][r] = v4.x;
    sT[cbase + i * 4 + 1][r] = v4.y;
    sT[cbase + i * 4 + 2][r] = v4.z;
    sT[cbase + i * 4 + 3][r] = v4.w;
  }
  __syncthreads();
  const int dl = t >> 2;
  const int kc = (t & 3) * 16;
  ushort_t* dst = WqT + (size_t)(td * 64 + dl) * ND + tk * 64 + kc;
  short8 o0, o1;
#pragma unroll
  for (int e = 0; e < 8; ++e) {
    o0[e] = (short)f2bf(sT[dl][kc + e]);
    o1[e] = (short)f2bf(sT[dl][kc + 8 + e]);
  }
  *(short8*)&dst[0] = o0;
  *(short8*)&dst[8] = o1;
}

// ---------------------------------------------------------------------------
// GEMM core (m97 structure, round-4 verified): Y[128,128] = A @ Bt^T + bias
// 256 thr = 4 waves 2x2; wave tile 64x64 = 4x4 mfma_f32_16x16x32_bf16; BK=32.
// ---------------------------------------------------------------------------
template <typename OutT>
__device__ __forceinline__ void gemm128x128(
    const ushort_t* __restrict__ A, const ushort_t* __restrict__ Bt,
    const float* __restrict__ bias, OutT* __restrict__ Y, int bm, int bn) {
  constexpr int K = 1024;
  constexpr int NY = 1024;
  __shared__ __align__(16) ushort_t sA[128 * 32];
  __shared__ __align__(16) ushort_t sB[128 * 32];
  const int t = threadIdx.x;
  const int lane = t & 63;
  const int w = t >> 6;
  const int wr = w >> 1, wc = w & 1;
  const int r15 = lane & 15, kh = lane >> 4;
  const int m0 = bm * 128, n0 = bn * 128;

  f32x4 acc[4][4] = {};

  const int row0 = t >> 2, cc8 = (t & 3) * 8;
  const ushort_t* gA0 = A + (size_t)(m0 + row0) * K + cc8;
  const ushort_t* gA1 = A + (size_t)(m0 + row0 + 64) * K + cc8;
  const ushort_t* gB0 = Bt + (size_t)(n0 + row0) * K + cc8;
  const ushort_t* gB1 = Bt + (size_t)(n0 + row0 + 64) * K + cc8;
  ushort_t* lA0 = &sA[t * 8];
  ushort_t* lA1 = &sA[(t + 256) * 8];
  ushort_t* lB0 = &sB[t * 8];
  ushort_t* lB1 = &sB[(t + 256) * 8];

  for (int k0 = 0; k0 < K; k0 += 32) {
    gload16(gA0 + k0, lA0);
    gload16(gA1 + k0, lA1);
    gload16(gB0 + k0, lB0);
    gload16(gB1 + k0, lB1);
    __syncthreads();
    short8 af[4], bfr[4];
#pragma unroll
    for (int m = 0; m < 4; ++m)
      af[m] = *(const short8*)&sA[(wr * 64 + m * 16 + r15) * 32 + kh * 8];
#pragma unroll
    for (int n = 0; n < 4; ++n)
      bfr[n] = *(const short8*)&sB[(wc * 64 + n * 16 + r15) * 32 + kh * 8];
#pragma unroll
    for (int m = 0; m < 4; ++m)
#pragma unroll
      for (int n = 0; n < 4; ++n)
        acc[m][n] = __builtin_amdgcn_mfma_f32_16x16x32_bf16(af[m], bfr[n],
                                                            acc[m][n], 0, 0, 0);
    __syncthreads();
  }

  const int orow0 = m0 + wr * 64 + kh * 4;
  const int ocol0 = n0 + wc * 64 + r15;
#pragma unroll
  for (int m = 0; m < 4; ++m) {
#pragma unroll
    for (int n = 0; n < 4; ++n) {
      const int col = ocol0 + n * 16;
      const float bv = bias ? bias[col] : 0.0f;
#pragma unroll
      for (int j = 0; j < 4; ++j) {
        const int row = orow0 + m * 16 + j;
        const float val = acc[m][n][j] + bv;
        if constexpr (__is_same(OutT, ushort_t))
          Y[(size_t)row * NY + col] = f2bf(val);
        else
          Y[(size_t)row * NY + col] = val;
      }
    }
  }
}

// ---------------------------------------------------------------------------
// GEMM core 64x128 (2 blocks/CU TLP variant, round-4 verified).
// ---------------------------------------------------------------------------
template <typename OutT>
__device__ __forceinline__ void gemm64x128(
    const ushort_t* __restrict__ A, const ushort_t* __restrict__ Bt,
    const float* __restrict__ bias, OutT* __restrict__ Y, int bm, int bn) {
  constexpr int K = 1024;
  constexpr int NY = 1024;
  __shared__ __align__(16) ushort_t sA[64 * 32];
  __shared__ __align__(16) ushort_t sB[128 * 32];
  const int t = threadIdx.x;
  const int lane = t & 63;
  const int w = t >> 6;
  const int wr = w >> 1, wc = w & 1;
  const int r15 = lane & 15, kh = lane >> 4;
  const int m0 = bm * 64, n0 = bn * 128;

  f32x4 acc[2][4] = {};

  const int rowA = t >> 2, cc8 = (t & 3) * 8;
  const ushort_t* gA = A + (size_t)(m0 + rowA) * K + cc8;
  const ushort_t* gB0 = Bt + (size_t)(n0 + rowA) * K + cc8;
  const ushort_t* gB1 = Bt + (size_t)(n0 + rowA + 64) * K + cc8;
  ushort_t* lA = &sA[t * 8];
  ushort_t* lB0 = &sB[t * 8];
  ushort_t* lB1 = &sB[(t + 256) * 8];

  for (int k0 = 0; k0 < K; k0 += 32) {
    gload16(gA + k0, lA);
    gload16(gB0 + k0, lB0);
    gload16(gB1 + k0, lB1);
    __syncthreads();
    short8 af[2], bfr[4];
#pragma unroll
    for (int m = 0; m < 2; ++m)
      af[m] = *(const short8*)&sA[(wr * 32 + m * 16 + r15) * 32 + kh * 8];
#pragma unroll
    for (int n = 0; n < 4; ++n)
      bfr[n] = *(const short8*)&sB[(wc * 64 + n * 16 + r15) * 32 + kh * 8];
#pragma unroll
    for (int m = 0; m < 2; ++m)
#pragma unroll
      for (int n = 0; n < 4; ++n)
        acc[m][n] = __builtin_amdgcn_mfma_f32_16x16x32_bf16(af[m], bfr[n],
                                                            acc[m][n], 0, 0, 0);
    __syncthreads();
  }

  const int orow0 = m0 + wr * 32 + kh * 4;
  const int ocol0 = n0 + wc * 64 + r15;
#pragma unroll
  for (int m = 0; m < 2; ++m) {
#pragma unroll
    for (int n = 0; n < 4; ++n) {
      const int col = ocol0 + n * 16;
      const float bv = bias ? bias[col] : 0.0f;
#pragma unroll
      for (int j = 0; j < 4; ++j) {
        const int row = orow0 + m * 16 + j;
        const float val = acc[m][n][j] + bv;
        if constexpr (__is_same(OutT, ushort_t))
          Y[(size_t)row * NY + col] = f2bf(val);
        else
          Y[(size_t)row * NY + col] = val;
      }
    }
  }
}

// K/V projections only (Q eliminated algebraically): grid 2*256, XCD-chunked.
__global__ __launch_bounds__(256) void proj_kv_kernel(
    const ushort_t* Xk, const ushort_t* Xv, const ushort_t* Wk,
    const ushort_t* Wv, const float* bk, const float* bv, ushort_t* Kb,
    ushort_t* Vb) {
  const int blk = blockIdx.x;
  const int tsel = blk >> 8;
  int rem = blk & 255;
  rem = (rem & 7) * 32 + (rem >> 3);  // XCD-chunked, bijective (256 % 8 == 0)
  const int bm = rem >> 3, bn = rem & 7;
  const ushort_t* A = tsel == 0 ? Xk : Xv;
  const ushort_t* Bt = tsel == 0 ? Wk : Wv;
  const float* bias = tsel == 0 ? bk : bv;
  ushort_t* Y = tsel == 0 ? Kb : Vb;
  gemm128x128<ushort_t>(A, Bt, bias, Y, bm, bn);
}

// E_b[j,d] = sum_k Ct_b[j,k] * WqT[d,k]   (biasless). grid 256, XCD-chunked.
__global__ __launch_bounds__(256) void e_gemm_kernel(const ushort_t* Ct,
                                                     const ushort_t* WqT,
                                                     ushort_t* E) {
  int blk = blockIdx.x;  // 0..255
  blk = (blk & 7) * 32 + (blk >> 3);  // bijective over 256
  const int b = blk >> 7;
  const int rem = blk & 127;
  const int bm = rem >> 3, bn = rem & 7;  // j-tile 0..15, d-tile 0..7
  const ushort_t* A = Ct + (size_t)b * ND * ND;
  ushort_t* Y = E + (size_t)b * ND * ND;
  gemm64x128<ushort_t>(A, WqT, nullptr, Y, bm, bn);
}

// Final: out[b] = Xq[b] @ E_b^T + fbias_b (fp32). grid 512, XCD-chunked.
__global__ __launch_bounds__(256) void out_gemm_kernel(const ushort_t* Xq,
                                                       const ushort_t* E,
                                                       const float* fbias,
                                                       float* out) {
  int blk = blockIdx.x;  // 0..511
  blk = (blk & 7) * 64 + (blk >> 3);  // bijective over 512
  const int bm = blk >> 3, bn = blk & 7;  // bm 0..63 (64-row tiles)
  const int batch = bm >> 5;
  const ushort_t* Bt = E + (size_t)batch * ND * ND;
  gemm64x128<float>(Xq, Bt, fbias + batch * ND, out, bm, bn);
}

// ---------------------------------------------------------------------------
// Mpart[bh][c][d1*64+d2] = sum_{s in chunk c} K[b,s,h*64+d1] * V[b,s,h*64+d2]
// ---------------------------------------------------------------------------
__global__ __launch_bounds__(256) void kv_outer_kernel(
    const ushort_t* __restrict__ Kb, const ushort_t* __restrict__ Vb,
    float* __restrict__ Mpart) {
  const int bh = blockIdx.x >> 4;
  const int c = blockIdx.x & 15;
  const int b = bh >> 4, h = bh & 15;
  __shared__ __align__(16) ushort_t sK[128][64];
  __shared__ __align__(16) ushort_t sV[128][64];
  const int t = threadIdx.x;
  const ushort_t* baseK = Kb + (size_t)(b * NS + c * 128) * ND + h * 64;
  const ushort_t* baseV = Vb + (size_t)(b * NS + c * 128) * ND + h * 64;
#pragma unroll
  for (int i = 0; i < 4; ++i) {
    const int ch = t + i * 256;
    const int row = ch >> 3, cc = ch & 7;
    *(short8*)&sK[row][cc * 8] = *(const short8*)&baseK[(size_t)row * ND + cc * 8];
    *(short8*)&sV[row][cc * 8] = *(const short8*)&baseV[(size_t)row * ND + cc * 8];
  }
  __syncthreads();
  const int d1 = (t & 15) * 4, d2 = (t >> 4) * 4;
  float acc[4][4] = {};
  for (int s = 0; s < 128; ++s) {
    const uint2 ku = *(const uint2*)&sK[s][d1];
    const uint2 vu = *(const uint2*)&sV[s][d2];
    float kx[4], vx[4];
    kx[0] = __uint_as_float(ku.x << 16);
    kx[1] = __uint_as_float(ku.x & 0xFFFF0000u);
    kx[2] = __uint_as_float(ku.y << 16);
    kx[3] = __uint_as_float(ku.y & 0xFFFF0000u);
    vx[0] = __uint_as_float(vu.x << 16);
    vx[1] = __uint_as_float(vu.x & 0xFFFF0000u);
    vx[2] = __uint_as_float(vu.y << 16);
    vx[3] = __uint_as_float(vu.y & 0xFFFF0000u);
#pragma unroll
    for (int a2 = 0; a2 < 4; ++a2)
#pragma unroll
      for (int b2 = 0; b2 < 4; ++b2) acc[a2][b2] += kx[a2] * vx[b2];
  }
  float* outp = Mpart + ((size_t)bh * 16 + c) * 4096;
#pragma unroll
  for (int a2 = 0; a2 < 4; ++a2)
#pragma unroll
    for (int b2 = 0; b2 < 4; ++b2)
      outp[(d1 + a2) * 64 + (d2 + b2)] = acc[a2][b2];
}

// Mred[bh][e] = (1/8) * sum_c Mpart[bh][c][e]
__global__ __launch_bounds__(256) void reduce_M_kernel(
    const float* __restrict__ Mpart, float* __restrict__ Mred) {
  const int idx = blockIdx.x * 256 + threadIdx.x;
  const int bh = idx >> 12, e = idx & 4095;
  float s = 0.f;
#pragma unroll
  for (int c = 0; c < 16; ++c) s += Mpart[((size_t)bh * 16 + c) * 4096 + e];
  Mred[idx] = s * 0.125f;
}

// ---------------------------------------------------------------------------
// Ct[b][j][k] = sum_i M[b,h(k)][k&63][i] * w_o[j][h(k)*64+i]
// ---------------------------------------------------------------------------
__global__ __launch_bounds__(256) void build_C_kernel(
    const float* __restrict__ Mred, const ushort_t* __restrict__ Wo,
    ushort_t* __restrict__ Ct) {
  const int blk = blockIdx.x;
  const int b = blk >> 8, h = (blk >> 4) & 15, jb = blk & 15;
  __shared__ float sM[64][65];
  __shared__ __align__(16) ushort_t sW[64][72];
  const int t = threadIdx.x;
  const float* Mp = Mred + (size_t)(b * 16 + h) * 4096;
#pragma unroll
  for (int i = 0; i < 16; ++i) {
    const int e = t + i * 256;
    sM[e >> 6][e & 63] = Mp[e];
  }
  const int j0 = jb * 64;
#pragma unroll
  for (int i = 0; i < 2; ++i) {
    const int ch = t + i * 256;
    const int row = ch >> 3, cc = ch & 7;
    *(short8*)&sW[row][cc * 8] =
        *(const short8*)&Wo[(size_t)(j0 + row) * ND + h * 64 + cc * 8];
  }
  __syncthreads();
  const int kk = (t & 15) * 4, jj = (t >> 4) * 4;
  float acc[4][4] = {};
  for (int i = 0; i < 64; ++i) {
    float mv[4], wv[4];
#pragma unroll
    for (int a2 = 0; a2 < 4; ++a2) mv[a2] = sM[kk + a2][i];
#pragma unroll
    for (int b2 = 0; b2 < 4; ++b2) wv[b2] = bf2f(sW[jj + b2][i]);
#pragma unroll
    for (int a2 = 0; a2 < 4; ++a2)
#pragma unroll
      for (int b2 = 0; b2 < 4; ++b2) acc[a2][b2] += mv[a2] * wv[b2];
  }
#pragma unroll
  for (int a2 = 0; a2 < 4; ++a2)
#pragma unroll
    for (int b2 = 0; b2 < 4; ++b2)
      Ct[((size_t)b * ND + j0 + jj + b2) * ND + h * 64 + kk + a2] =
          f2bf(acc[a2][b2]);
}

// fbias[b][j] = sum_k bq[k]*Ct_b[j,k] + bo[j].  grid 16, 256 thr.
__global__ __launch_bounds__(256) void f_kernel(const ushort_t* __restrict__ Ct,
                                                const float* __restrict__ bq,
                                                const float* __restrict__ bo,
                                                float* __restrict__ fbias) {
  const int b = blockIdx.x >> 3;
  const int j = (blockIdx.x & 7) * 128 + (threadIdx.x >> 1);
  const int half = threadIdx.x & 1;
  const ushort_t* row = Ct + ((size_t)b * ND + j) * ND + half * 512;
  const float* bqh = bq + half * 512;
  float s = 0.f;
  for (int c = 0; c < 64; ++c) {
    const short8 v8 = *(const short8*)&row[c * 8];
#pragma unroll
    for (int e = 0; e < 8; ++e) s += bf2f((ushort_t)v8[e]) * bqh[c * 8 + e];
  }
  __shared__ float red[256];
  red[threadIdx.x] = s;
  __syncthreads();
  if (half == 0) fbias[b * ND + j] = red[threadIdx.x] + red[threadIdx.x + 1] + bo[j];
}

// ---------------------------------------------------------------------------
extern "C" void kernel_launch(void* const* d_in, const int* in_sizes, int n_in,
                              void* d_out, int out_size, void* d_ws,
                              size_t ws_size, hipStream_t stream) {
  (void)in_sizes; (void)n_in; (void)out_size; (void)ws_size;
  const float* q = (const float*)d_in[0];
  const float* k = (const float*)d_in[1];
  const float* v = (const float*)d_in[2];
  const float* wq = (const float*)d_in[3];
  const float* bq = (const float*)d_in[4];
  const float* wk = (const float*)d_in[5];
  const float* bk = (const float*)d_in[6];
  const float* wv = (const float*)d_in[7];
  const float* bv = (const float*)d_in[8];
  const float* wo = (const float*)d_in[9];
  const float* bo = (const float*)d_in[10];
  float* out = (float*)d_out;

  const size_t MB = 1048576;
  char* ws = (char*)d_ws;
  ushort_t* Xq = (ushort_t*)(ws + 0 * MB);   // 8 MB, live until final GEMM
  ushort_t* Xk = (ushort_t*)(ws + 8 * MB);   // 8 MB, dead after proj_kv
  ushort_t* Xv = (ushort_t*)(ws + 16 * MB);  // 8 MB, dead after proj_kv
  ushort_t* Wk = (ushort_t*)(ws + 24 * MB);  // 2 MB, dead after proj_kv
  ushort_t* Wv = (ushort_t*)(ws + 26 * MB);  // 2 MB, dead after proj_kv
  ushort_t* Wo = (ushort_t*)(ws + 28 * MB);  // 2 MB, live until build_C
  ushort_t* WqT = (ushort_t*)(ws + 30 * MB); // 2 MB, live until e_gemm
  ushort_t* Kb = (ushort_t*)(ws + 32 * MB);  // 8 MB
  ushort_t* Vb = (ushort_t*)(ws + 40 * MB);  // 8 MB   (total 48 MB)
  // overlays (written only after their base region is dead)
  float* Mpart = (float*)(ws + 8 * MB);                 // 8 MB over Xk
  float* Mred = (float*)(ws + 16 * MB);                 // 512 KB over Xv
  ushort_t* Ct = (ushort_t*)(ws + 16 * MB + 524288);    // 4 MB over Xv
  float* fbias = (float*)(ws + 16 * MB + 524288 + 4 * MB);  // 8 KB over Xv
  ushort_t* E = (ushort_t*)(ws + 24 * MB);              // 4 MB over Wk+Wv

  hipLaunchKernelGGL(convert_kernel, dim3(7680), dim3(256), 0, stream, q, k, v,
                     wk, wv, wo, Xq, Xk, Xv, Wk, Wv, Wo);
  hipLaunchKernelGGL(transp_wq_kernel, dim3(256), dim3(256), 0, stream, wq,
                     WqT);
  hipLaunchKernelGGL(proj_kv_kernel, dim3(512), dim3(256), 0, stream, Xk, Xv,
                     Wk, Wv, bk, bv, Kb, Vb);
  hipLaunchKernelGGL(kv_outer_kernel, dim3(512), dim3(256), 0, stream, Kb, Vb,
                     Mpart);
  hipLaunchKernelGGL(reduce_M_kernel, dim3(512), dim3(256), 0, stream, Mpart,
                     Mred);
  hipLaunchKernelGGL(build_C_kernel, dim3(512), dim3(256), 0, stream, Mred, Wo,
                     Ct);
  hipLaunchKernelGGL(f_kernel, dim3(16), dim3(256), 0, stream, Ct, bq, bo,
                     fbias);
  hipLaunchKernelGGL(e_gemm_kernel, dim3(256), dim3(256), 0, stream, Ct, WqT,
                     E);
  hipLaunchKernelGGL(out_gemm_kernel, dim3(512), dim3(256), 0, stream, Xq, E,
                     fbias, out);
}

// Round 9
// 210.963 us; speedup vs baseline: 1.0861x; 1.0861x over previous
//
#include <hip/hip_runtime.h>
#include <hip/hip_bf16.h>

typedef unsigned short ushort_t;
typedef unsigned int uint32;
typedef __attribute__((ext_vector_type(8))) short short8;
typedef __attribute__((ext_vector_type(4))) float f32x4;

// Problem constants: B=2, S=2048, D=1024, H=16, DK=64
#define NB 2
#define NS 2048
#define ND 1024
#define NH 16

__device__ __forceinline__ float bf2f(ushort_t u) {
  return __uint_as_float(((uint32)u) << 16);
}
__device__ __forceinline__ ushort_t f2bf(float x) {
  uint32 u = __float_as_uint(x);
  uint32 r = u + 0x7FFFu + ((u >> 16) & 1u);  // RNE
  return (ushort_t)(r >> 16);
}

__device__ __forceinline__ void gload16(const void* g, void* l) {
  __builtin_amdgcn_global_load_lds(
      (const __attribute__((address_space(1))) void*)g,
      (__attribute__((address_space(3))) void*)l, 16, 0, 0);
}

// ---------------------------------------------------------------------------
// fp32 -> bf16 convert: q,k,v (2048 blocks each), wq,wk,wv,wo (512 each),
// plus 64 blocks that zero Mred (32*4096 f32). Grid 8256.
// ---------------------------------------------------------------------------
__global__ __launch_bounds__(256) void convert_kernel(
    const float* q, const float* k, const float* v, const float* wq,
    const float* wk, const float* wv, const float* wo, ushort_t* Xq,
    ushort_t* Xk, ushort_t* Xv, ushort_t* Wq, ushort_t* Wk, ushort_t* Wv,
    ushort_t* Wo, float* Mred) {
  const int blk = blockIdx.x;
  if (blk >= 8192) {  // zero Mred: 64 blocks x 2048 floats
    const size_t o = (size_t)(blk - 8192) * 2048 + (size_t)threadIdx.x * 8;
    const float4 z = make_float4(0.f, 0.f, 0.f, 0.f);
    *(float4*)&Mred[o] = z;
    *(float4*)&Mred[o + 4] = z;
    return;
  }
  const float* src;
  ushort_t* dst;
  int base;
  if (blk < 2048) { src = q; dst = Xq; base = blk; }
  else if (blk < 4096) { src = k; dst = Xk; base = blk - 2048; }
  else if (blk < 6144) { src = v; dst = Xv; base = blk - 4096; }
  else if (blk < 6656) { src = wq; dst = Wq; base = blk - 6144; }
  else if (blk < 7168) { src = wk; dst = Wk; base = blk - 6656; }
  else if (blk < 7680) { src = wv; dst = Wv; base = blk - 7168; }
  else { src = wo; dst = Wo; base = blk - 7680; }
  const size_t off = (size_t)base * 2048 + (size_t)threadIdx.x * 8;
  const float4 v0 = *(const float4*)&src[off];
  const float4 v1 = *(const float4*)&src[off + 4];
  short8 o;
  o[0] = (short)f2bf(v0.x); o[1] = (short)f2bf(v0.y);
  o[2] = (short)f2bf(v0.z); o[3] = (short)f2bf(v0.w);
  o[4] = (short)f2bf(v1.x); o[5] = (short)f2bf(v1.y);
  o[6] = (short)f2bf(v1.z); o[7] = (short)f2bf(v1.w);
  *(short8*)&dst[off] = o;
}

// ---------------------------------------------------------------------------
// GEMM core, BK=64, source-pre-swizzled LDS (T2 both-sides, rule #21):
// LDS tile [128][64] bf16 (128B rows). Physical slot p at row r holds global
// col-block (p ^ (r&7)); reads XOR the same way -> conflict-free b128 reads.
// Y[128,128] = A @ Bt^T + bias. 4 waves 2x2, wave tile 64x64, 32 MFMA/drain.
// ---------------------------------------------------------------------------
template <typename OutT>
__device__ __forceinline__ void gemm128x128_bk64(
    const ushort_t* __restrict__ A, const ushort_t* __restrict__ Bt,
    const float* __restrict__ bias, OutT* __restrict__ Y, int bm, int bn) {
  constexpr int K = 1024;
  constexpr int NY = 1024;
  __shared__ __align__(16) ushort_t sA[128 * 64];
  __shared__ __align__(16) ushort_t sB[128 * 64];
  const int t = threadIdx.x;
  const int lane = t & 63;
  const int w = t >> 6;
  const int wr = w >> 1, wc = w & 1;
  const int r15 = lane & 15, kh = lane >> 4;
  const int m0 = bm * 128, n0 = bn * 128;

  f32x4 acc[4][4] = {};

  // chunk c = t + i*256 -> row=(t>>3)+i*32, phys slot=t&7; src slot=phys^(row&7)
  const int rowS = t >> 3;
  const int srcSlot = (t & 7) ^ (rowS & 7);  // i*32 preserves row&7
  const ushort_t* gA = A + (size_t)(m0 + rowS) * K + srcSlot * 8;
  const ushort_t* gB = Bt + (size_t)(n0 + rowS) * K + srcSlot * 8;

  for (int k0 = 0; k0 < K; k0 += 64) {
#pragma unroll
    for (int i = 0; i < 4; ++i) {
      gload16(gA + (size_t)(i * 32) * K + k0, &sA[(t + i * 256) * 8]);
      gload16(gB + (size_t)(i * 32) * K + k0, &sB[(t + i * 256) * 8]);
    }
    __syncthreads();  // drain (16 total, was 32 at BK=32)
#pragma unroll
    for (int kk = 0; kk < 2; ++kk) {
      const int slotbase = kk * 4 + kh;  // logical 8-elem slot 0..7
      short8 af[4], bfr[4];
#pragma unroll
      for (int m = 0; m < 4; ++m) {
        const int row = wr * 64 + m * 16 + r15;
        af[m] = *(const short8*)&sA[row * 64 + ((slotbase ^ (row & 7)) * 8)];
      }
#pragma unroll
      for (int n = 0; n < 4; ++n) {
        const int row = wc * 64 + n * 16 + r15;
        bfr[n] = *(const short8*)&sB[row * 64 + ((slotbase ^ (row & 7)) * 8)];
      }
#pragma unroll
      for (int m = 0; m < 4; ++m)
#pragma unroll
        for (int n = 0; n < 4; ++n)
          acc[m][n] = __builtin_amdgcn_mfma_f32_16x16x32_bf16(
              af[m], bfr[n], acc[m][n], 0, 0, 0);
    }
    __syncthreads();
  }

  // epilogue: C/D layout col=lane&15, row=(lane>>4)*4+reg  [verified m89/m91]
  const int orow0 = m0 + wr * 64 + kh * 4;
  const int ocol0 = n0 + wc * 64 + r15;
#pragma unroll
  for (int m = 0; m < 4; ++m) {
#pragma unroll
    for (int n = 0; n < 4; ++n) {
      const int col = ocol0 + n * 16;
      const float bv = bias[col];
#pragma unroll
      for (int j = 0; j < 4; ++j) {
        const int row = orow0 + m * 16 + j;
        const float val = acc[m][n][j] + bv;
        if constexpr (__is_same(OutT, ushort_t))
          Y[(size_t)row * NY + col] = f2bf(val);
        else
          Y[(size_t)row * NY + col] = val;
      }
    }
  }
}

// ---------------------------------------------------------------------------
// GEMM core 64x128, BK=64, same swizzle. 2 blocks/CU TLP variant.
// ---------------------------------------------------------------------------
template <typename OutT>
__device__ __forceinline__ void gemm64x128_bk64(
    const ushort_t* __restrict__ A, const ushort_t* __restrict__ Bt,
    const float* __restrict__ bias, OutT* __restrict__ Y, int bm, int bn) {
  constexpr int K = 1024;
  constexpr int NY = 1024;
  __shared__ __align__(16) ushort_t sA[64 * 64];
  __shared__ __align__(16) ushort_t sB[128 * 64];
  const int t = threadIdx.x;
  const int lane = t & 63;
  const int w = t >> 6;
  const int wr = w >> 1, wc = w & 1;
  const int r15 = lane & 15, kh = lane >> 4;
  const int m0 = bm * 64, n0 = bn * 128;

  f32x4 acc[2][4] = {};

  const int rowS = t >> 3;
  const int srcSlot = (t & 7) ^ (rowS & 7);
  const ushort_t* gA = A + (size_t)(m0 + rowS) * K + srcSlot * 8;
  const ushort_t* gB = Bt + (size_t)(n0 + rowS) * K + srcSlot * 8;

  for (int k0 = 0; k0 < K; k0 += 64) {
#pragma unroll
    for (int i = 0; i < 2; ++i)
      gload16(gA + (size_t)(i * 32) * K + k0, &sA[(t + i * 256) * 8]);
#pragma unroll
    for (int i = 0; i < 4; ++i)
      gload16(gB + (size_t)(i * 32) * K + k0, &sB[(t + i * 256) * 8]);
    __syncthreads();
#pragma unroll
    for (int kk = 0; kk < 2; ++kk) {
      const int slotbase = kk * 4 + kh;
      short8 af[2], bfr[4];
#pragma unroll
      for (int m = 0; m < 2; ++m) {
        const int row = wr * 32 + m * 16 + r15;
        af[m] = *(const short8*)&sA[row * 64 + ((slotbase ^ (row & 7)) * 8)];
      }
#pragma unroll
      for (int n = 0; n < 4; ++n) {
        const int row = wc * 64 + n * 16 + r15;
        bfr[n] = *(const short8*)&sB[row * 64 + ((slotbase ^ (row & 7)) * 8)];
      }
#pragma unroll
      for (int m = 0; m < 2; ++m)
#pragma unroll
        for (int n = 0; n < 4; ++n)
          acc[m][n] = __builtin_amdgcn_mfma_f32_16x16x32_bf16(
              af[m], bfr[n], acc[m][n], 0, 0, 0);
    }
    __syncthreads();
  }

  const int orow0 = m0 + wr * 32 + kh * 4;
  const int ocol0 = n0 + wc * 64 + r15;
#pragma unroll
  for (int m = 0; m < 2; ++m) {
#pragma unroll
    for (int n = 0; n < 4; ++n) {
      const int col = ocol0 + n * 16;
      const float bv = bias[col];
#pragma unroll
      for (int j = 0; j < 4; ++j) {
        const int row = orow0 + m * 16 + j;
        const float val = acc[m][n][j] + bv;
        if constexpr (__is_same(OutT, ushort_t))
          Y[(size_t)row * NY + col] = f2bf(val);
        else
          Y[(size_t)row * NY + col] = val;
      }
    }
  }
}

// Fused Q/K/V projections: grid 3*256, XCD-chunked within each tensor group.
__global__ __launch_bounds__(256) void proj_qkv_kernel(
    const ushort_t* Xq, const ushort_t* Xk, const ushort_t* Xv,
    const ushort_t* Wq, const ushort_t* Wk, const ushort_t* Wv,
    const float* bq, const float* bk, const float* bv,
    ushort_t* Qb, ushort_t* Kb, ushort_t* Vb) {
  const int blk = blockIdx.x;
  const int tsel = blk >> 8;
  int rem = blk & 255;
  rem = (rem & 7) * 32 + (rem >> 3);  // XCD-chunked, bijective (256 % 8 == 0)
  const int bm = rem >> 3, bn = rem & 7;
  const ushort_t* A = tsel == 0 ? Xq : (tsel == 1 ? Xk : Xv);
  const ushort_t* Bt = tsel == 0 ? Wq : (tsel == 1 ? Wk : Wv);
  const float* bias = tsel == 0 ? bq : (tsel == 1 ? bk : bv);
  ushort_t* Y = tsel == 0 ? Qb : (tsel == 1 ? Kb : Vb);
  gemm128x128_bk64<ushort_t>(A, Bt, bias, Y, bm, bn);
}

// Final: out = Qb @ Ct[batch]^T + b_o (fp32). grid 512, XCD-chunked.
__global__ __launch_bounds__(256) void out_gemm_kernel(
    const ushort_t* Qb, const ushort_t* Ct, const float* bo, float* out) {
  int blk = blockIdx.x;  // 0..511
  blk = (blk & 7) * 64 + (blk >> 3);  // bijective (512 % 8 == 0)
  const int bm = blk >> 3, bn = blk & 7;  // 64-row tiles; 32 per batch
  const ushort_t* Bt = Ct + (size_t)(bm >> 5) * 1024 * 1024;
  gemm64x128_bk64<float>(Qb, Bt, bo, out, bm, bn);
}

// ---------------------------------------------------------------------------
// Mred[bh][d1*64+d2] += sum_{s in chunk} K[b,s,h*64+d1]*V[b,s,h*64+d2]
// (unscaled; /8 folded into build_C). fp32 atomics, 16 adds per address.
// ---------------------------------------------------------------------------
__global__ __launch_bounds__(256) void kv_outer_kernel(
    const ushort_t* __restrict__ Kb, const ushort_t* __restrict__ Vb,
    float* __restrict__ Mred) {
  const int bh = blockIdx.x >> 4;
  const int c = blockIdx.x & 15;
  const int b = bh >> 4, h = bh & 15;
  __shared__ __align__(16) ushort_t sK[128][64];
  __shared__ __align__(16) ushort_t sV[128][64];
  const int t = threadIdx.x;
  const ushort_t* baseK = Kb + (size_t)(b * NS + c * 128) * ND + h * 64;
  const ushort_t* baseV = Vb + (size_t)(b * NS + c * 128) * ND + h * 64;
#pragma unroll
  for (int i = 0; i < 4; ++i) {
    const int ch = t + i * 256;
    const int row = ch >> 3, cc = ch & 7;
    *(short8*)&sK[row][cc * 8] = *(const short8*)&baseK[(size_t)row * ND + cc * 8];
    *(short8*)&sV[row][cc * 8] = *(const short8*)&baseV[(size_t)row * ND + cc * 8];
  }
  __syncthreads();
  const int d1 = (t & 15) * 4, d2 = (t >> 4) * 4;
  float acc[4][4] = {};
  for (int s = 0; s < 128; ++s) {
    const uint2 ku = *(const uint2*)&sK[s][d1];
    const uint2 vu = *(const uint2*)&sV[s][d2];
    float kx[4], vx[4];
    kx[0] = __uint_as_float(ku.x << 16);
    kx[1] = __uint_as_float(ku.x & 0xFFFF0000u);
    kx[2] = __uint_as_float(ku.y << 16);
    kx[3] = __uint_as_float(ku.y & 0xFFFF0000u);
    vx[0] = __uint_as_float(vu.x << 16);
    vx[1] = __uint_as_float(vu.x & 0xFFFF0000u);
    vx[2] = __uint_as_float(vu.y << 16);
    vx[3] = __uint_as_float(vu.y & 0xFFFF0000u);
#pragma unroll
    for (int a2 = 0; a2 < 4; ++a2)
#pragma unroll
      for (int b2 = 0; b2 < 4; ++b2) acc[a2][b2] += kx[a2] * vx[b2];
  }
  float* outp = Mred + (size_t)bh * 4096;
#pragma unroll
  for (int a2 = 0; a2 < 4; ++a2)
#pragma unroll
    for (int b2 = 0; b2 < 4; ++b2)
      atomicAdd(&outp[(d1 + a2) * 64 + (d2 + b2)], acc[a2][b2]);
}

// ---------------------------------------------------------------------------
// Ct[b][j][k] = 0.125 * sum_i M[b,h(k)][k&63][i] * w_o[j][h(k)*64+i]
// ---------------------------------------------------------------------------
__global__ __launch_bounds__(256) void build_C_kernel(
    const float* __restrict__ Mred, const ushort_t* __restrict__ Wo,
    ushort_t* __restrict__ Ct) {
  const int blk = blockIdx.x;
  const int b = blk >> 8, h = (blk >> 4) & 15, jb = blk & 15;
  __shared__ float sM[64][65];
  __shared__ __align__(16) ushort_t sW[64][72];
  const int t = threadIdx.x;
  const float* Mp = Mred + (size_t)(b * 16 + h) * 4096;
#pragma unroll
  for (int i = 0; i < 16; ++i) {
    const int e = t + i * 256;
    sM[e >> 6][e & 63] = Mp[e];
  }
  const int j0 = jb * 64;
#pragma unroll
  for (int i = 0; i < 2; ++i) {
    const int ch = t + i * 256;
    const int row = ch >> 3, cc = ch & 7;
    *(short8*)&sW[row][cc * 8] =
        *(const short8*)&Wo[(size_t)(j0 + row) * ND + h * 64 + cc * 8];
  }
  __syncthreads();
  const int kk = (t & 15) * 4, jj = (t >> 4) * 4;
  float acc[4][4] = {};
  for (int i = 0; i < 64; ++i) {
    float mv[4], wv[4];
#pragma unroll
    for (int a2 = 0; a2 < 4; ++a2) mv[a2] = sM[kk + a2][i];
#pragma unroll
    for (int b2 = 0; b2 < 4; ++b2) wv[b2] = bf2f(sW[jj + b2][i]);
#pragma unroll
    for (int a2 = 0; a2 < 4; ++a2)
#pragma unroll
      for (int b2 = 0; b2 < 4; ++b2) acc[a2][b2] += mv[a2] * wv[b2];
  }
#pragma unroll
  for (int a2 = 0; a2 < 4; ++a2)
#pragma unroll
    for (int b2 = 0; b2 < 4; ++b2)
      Ct[((size_t)b * ND + j0 + jj + b2) * ND + h * 64 + kk + a2] =
          f2bf(acc[a2][b2] * 0.125f);
}

// ---------------------------------------------------------------------------
extern "C" void kernel_launch(void* const* d_in, const int* in_sizes, int n_in,
                              void* d_out, int out_size, void* d_ws,
                              size_t ws_size, hipStream_t stream) {
  (void)in_sizes; (void)n_in; (void)out_size; (void)ws_size;
  const float* q = (const float*)d_in[0];
  const float* k = (const float*)d_in[1];
  const float* v = (const float*)d_in[2];
  const float* wq = (const float*)d_in[3];
  const float* bq = (const float*)d_in[4];
  const float* wk = (const float*)d_in[5];
  const float* bk = (const float*)d_in[6];
  const float* wv = (const float*)d_in[7];
  const float* bv = (const float*)d_in[8];
  const float* wo = (const float*)d_in[9];
  const float* bo = (const float*)d_in[10];
  float* out = (float*)d_out;

  const size_t MB = 1048576;
  char* ws = (char*)d_ws;  // flat layout, no overlays (61.5 MB used)
  ushort_t* Xq = (ushort_t*)(ws + 0 * MB);    // 8 MB
  ushort_t* Xk = (ushort_t*)(ws + 8 * MB);    // 8 MB
  ushort_t* Xv = (ushort_t*)(ws + 16 * MB);   // 8 MB
  ushort_t* Wq = (ushort_t*)(ws + 24 * MB);   // 2 MB
  ushort_t* Wk = (ushort_t*)(ws + 26 * MB);   // 2 MB
  ushort_t* Wv = (ushort_t*)(ws + 28 * MB);   // 2 MB
  ushort_t* Wo = (ushort_t*)(ws + 30 * MB);   // 2 MB
  ushort_t* Qb = (ushort_t*)(ws + 32 * MB);   // 8 MB
  ushort_t* Kb = (ushort_t*)(ws + 40 * MB);   // 8 MB
  ushort_t* Vb = (ushort_t*)(ws + 48 * MB);   // 8 MB
  float* Mred = (float*)(ws + 56 * MB);       // 512 KB [32][4096] f32
  ushort_t* Ct = (ushort_t*)(ws + 57 * MB);   // 4 MB [2][1024][1024] bf16

  hipLaunchKernelGGL(convert_kernel, dim3(8256), dim3(256), 0, stream, q, k, v,
                     wq, wk, wv, wo, Xq, Xk, Xv, Wq, Wk, Wv, Wo, Mred);
  hipLaunchKernelGGL(proj_qkv_kernel, dim3(768), dim3(256), 0, stream, Xq, Xk,
                     Xv, Wq, Wk, Wv, bq, bk, bv, Qb, Kb, Vb);
  hipLaunchKernelGGL(kv_outer_kernel, dim3(512), dim3(256), 0, stream, Kb, Vb,
                     Mred);
  hipLaunchKernelGGL(build_C_kernel, dim3(512), dim3(256), 0, stream, Mred, Wo,
                     Ct);
  hipLaunchKernelGGL(out_gemm_kernel, dim3(512), dim3(256), 0, stream, Qb, Ct,
                     bo, out);
}